// Round 12
// baseline (250.479 us; speedup 1.0000x reference)
//
#include <hip/hip_runtime.h>
#include <hip/hip_bf16.h>
#include <cstddef>

// B=4, T=144, N=256, H=64, NC=4, CH=9, BT=576.
// Chain: prep -> gatA -> gatBF -> k_lstm (dedicated, 64-thr blocks, f16-dot2, no barriers)
//        -> k_ctx2 (ctxL + GRU/ctxS) -> lin1 -> lin2 -> conv.
// (~85 us of dur_us is an irreducible harness ws-fill.)

typedef __attribute__((ext_vector_type(8))) short bf16x8;
typedef __attribute__((ext_vector_type(4))) float f32x4;
typedef __fp16 h16x2 __attribute__((ext_vector_type(2)));

#if __has_builtin(__builtin_amdgcn_fdot2)
#define DOT2(a, b, c) __builtin_amdgcn_fdot2((a), (b), (c), false)
#else
#define DOT2(a, b, c) ((c) + (float)(a)[0] * (float)(b)[0] + (float)(a)[1] * (float)(b)[1])
#endif

__device__ __forceinline__ float rcp_(float x) { return __builtin_amdgcn_rcpf(x); }
__device__ __forceinline__ float sigf(float x) { return rcp_(1.0f + __expf(-x)); }
__device__ __forceinline__ float tanh_(float x) {
    x = fminf(fmaxf(x, -15.f), 15.f);
    float e = __expf(2.f * x);
    return (e - 1.f) * rcp_(e + 1.f);
}
__device__ __forceinline__ unsigned short f2b(float f) {
    unsigned u = __float_as_uint(f);
    u += 0x7FFFu + ((u >> 16) & 1u);
    return (unsigned short)(u >> 16);
}
__device__ __forceinline__ unsigned pk2(float lo, float hi) {
    __hip_bfloat162 h = __float22bfloat162_rn(float2{lo, hi});
    return *reinterpret_cast<unsigned*>(&h);
}
__device__ __forceinline__ float b2f(short s) {
    return __uint_as_float(((unsigned)(unsigned short)s) << 16);
}
__device__ __forceinline__ unsigned h2u(h16x2 v) { return *reinterpret_cast<unsigned*>(&v); }
__device__ __forceinline__ h16x2 u2h(unsigned u) { return *reinterpret_cast<h16x2*>(&u); }

// ---------- K1: Mb bf16 mask ; Wt bf16 [64 cols][256 k] ----------
__global__ void k_prep(const float* __restrict__ adj, const float* __restrict__ dist,
                       const float* __restrict__ W_gat,
                       unsigned short* __restrict__ Mb, unsigned short* __restrict__ Wt) {
    int blk = blockIdx.x, tid = threadIdx.x;
    if (blk < 256) {
        int i = blk * 256 + tid;
        Mb[i] = f2b((adj[i] > 0.f) ? -dist[i] : -1e9f);
    } else {
        for (int it = 0; it < 64; ++it) {
            int e = it * 256 + tid;
            int k = e >> 6, c = e & 63;
            Wt[c * 256 + k] = f2b(W_gat[e]);
        }
    }
}

// ---------- K2a: Wh GEMM. 2304 blocks (bt = blk>>2, sub = blk&3), 64 rows each ----------
__global__ __launch_bounds__(256, 6) void k_gatA(
    const float* __restrict__ seg, const unsigned short* __restrict__ Wt,
    const float* __restrict__ a_src, const float* __restrict__ a_dst,
    unsigned short* __restrict__ WhT, float* __restrict__ svec, float* __restrict__ dvec,
    float* __restrict__ smaxp, float* __restrict__ dmaxp) {
    __shared__ __align__(16) short A_s[64 * 64];
    __shared__ float red[8];

    const int tid  = threadIdx.x;
    const int lane = tid & 63;
    const int wv   = tid >> 6;
    const int blk  = blockIdx.x;
    const int bt   = blk >> 2;
    const int sub  = blk & 3;
    const float* __restrict__ segp = seg + (size_t)bt * 65536 + sub * 64 * 256;

    f32x4 acc[4];
    #pragma unroll
    for (int n = 0; n < 4; ++n) acc[n] = (f32x4)(0.f);

    for (int kc = 0; kc < 4; ++kc) {
        #pragma unroll
        for (int it = 0; it < 2; ++it) {
            int unit = it * 256 + tid;
            int row = unit >> 3, u = unit & 7;
            const float* g = segp + row * 256 + kc * 64 + u * 8;
            f32x4 v0 = *(const f32x4*)g;
            f32x4 v1 = *(const f32x4*)(g + 4);
            uint4 pk;
            pk.x = pk2(v0[0], v0[1]); pk.y = pk2(v0[2], v0[3]);
            pk.z = pk2(v1[0], v1[1]); pk.w = pk2(v1[2], v1[3]);
            *(uint4*)&A_s[(row * 8 + (u ^ (row & 7))) * 8] = pk;
        }
        bf16x8 bfr[2][4];
        #pragma unroll
        for (int kt2 = 0; kt2 < 2; ++kt2) {
            int ku = kt2 * 4 + (lane >> 4);
            #pragma unroll
            for (int nt = 0; nt < 4; ++nt) {
                int col = nt * 16 + (lane & 15);
                bfr[kt2][nt] = *(const bf16x8*)(Wt + col * 256 + kc * 64 + ku * 8);
            }
        }
        __syncthreads();
        int arow = wv * 16 + (lane & 15);
        #pragma unroll
        for (int kt2 = 0; kt2 < 2; ++kt2) {
            int ku = kt2 * 4 + (lane >> 4);
            bf16x8 afr = *(const bf16x8*)&A_s[(arow * 8 + (ku ^ (arow & 7))) * 8];
            #pragma unroll
            for (int nt = 0; nt < 4; ++nt)
                acc[nt] = __builtin_amdgcn_mfma_f32_16x16x32_bf16(afr, bfr[kt2][nt], acc[nt], 0, 0, 0);
        }
        __syncthreads();
    }

    float asv[4], adv[4];
    #pragma unroll
    for (int nt = 0; nt < 4; ++nt) {
        asv[nt] = a_src[nt * 16 + (lane & 15)];
        adv[nt] = a_dst[nt * 16 + (lane & 15)];
    }
    float mxs = -3e38f, mxd = -3e38f;
    int rowbase = sub * 64 + wv * 16;
    #pragma unroll
    for (int r = 0; r < 4; ++r) {
        float ps = acc[0][r] * asv[0] + acc[1][r] * asv[1] + acc[2][r] * asv[2] + acc[3][r] * asv[3];
        float pd = acc[0][r] * adv[0] + acc[1][r] * adv[1] + acc[2][r] * adv[2] + acc[3][r] * adv[3];
        #pragma unroll
        for (int m = 1; m < 16; m <<= 1) { ps += __shfl_xor(ps, m); pd += __shfl_xor(pd, m); }
        if ((lane & 15) == 0) {
            int row = rowbase + (lane >> 4) * 4 + r;
            svec[bt * 256 + row] = ps;
            dvec[bt * 256 + row] = pd;
        }
        mxs = fmaxf(mxs, ps); mxd = fmaxf(mxd, pd);
    }
    mxs = fmaxf(mxs, __shfl_xor(mxs, 16)); mxs = fmaxf(mxs, __shfl_xor(mxs, 32));
    mxd = fmaxf(mxd, __shfl_xor(mxd, 16)); mxd = fmaxf(mxd, __shfl_xor(mxd, 32));
    if (lane == 0) { red[wv] = mxs; red[4 + wv] = mxd; }

    {
        int c = lane & 15, q = lane >> 4;
        int kt2  = wv >> 1;
        int oct  = (wv & 1) * 2 + (q >> 1);
        int laneP = oct * 16 + c;
        int e0b  = (q & 1) * 8;
        #pragma unroll
        for (int nt = 0; nt < 4; ++nt) {
            uint2 pk4;
            pk4.x = pk2(acc[nt][0], acc[nt][1]);
            pk4.y = pk2(acc[nt][2], acc[nt][3]);
            *(uint2*)((char*)A_s + (((kt2 * 4 + nt) * 64 + laneP) * 16 + e0b)) = pk4;
        }
    }
    __syncthreads();
    {
        const uint4* Fs = (const uint4*)A_s;
        uint4* Gd = (uint4*)(WhT + (size_t)bt * 16384 + sub * 4096);
        Gd[tid] = Fs[tid];
        Gd[256 + tid] = Fs[256 + tid];
    }
    if (tid == 0) {
        smaxp[blk] = fmaxf(fmaxf(red[0], red[1]), fmaxf(red[2], red[3]));
        dmaxp[blk] = fmaxf(fmaxf(red[4], red[5]), fmaxf(red[6], red[7]));
    }
}

// ---------- K2b: fused exp+PV+normalize+elu+mean+gx. One block per bt (576 blocks) ----------
__global__ __launch_bounds__(256, 4) void k_gatBF(
    const unsigned short* __restrict__ WhT, const float* __restrict__ svec,
    const float* __restrict__ dvec, const float* __restrict__ smaxp,
    const float* __restrict__ dmaxp, const unsigned short* __restrict__ Mb,
    const float* __restrict__ lWih, const float* __restrict__ lbih,
    const float* __restrict__ lbhh, float* __restrict__ feats, float* __restrict__ gx) {
    __shared__ __align__(16) float dv_l[256];
    __shared__ float red[256];
    __shared__ __align__(16) float feats_l[64];

    const int tid  = threadIdx.x;
    const int lane = tid & 63;
    const int wv   = tid >> 6;
    const int wrow = wv * 64;
    const int bt   = blockIdx.x;
    const unsigned short* __restrict__ Wp = WhT + (size_t)bt * 16384;

    dv_l[tid] = dvec[bt * 256 + tid];
    float mB;
    {
        float ms = fmaxf(fmaxf(smaxp[bt * 4], smaxp[bt * 4 + 1]),
                         fmaxf(smaxp[bt * 4 + 2], smaxp[bt * 4 + 3]));
        float md = fmaxf(fmaxf(dmaxp[bt * 4], dmaxp[bt * 4 + 1]),
                         fmaxf(dmaxp[bt * 4 + 2], dmaxp[bt * 4 + 3]));
        float x = ms + md;
        mB = fmaxf(x, 0.2f * x);
    }
    float sv4[4];
    #pragma unroll
    for (int mt = 0; mt < 4; ++mt) sv4[mt] = svec[bt * 256 + wrow + mt * 16 + (lane & 15)];
    __syncthreads();

    f32x4 acc2[4][4];
    #pragma unroll
    for (int a = 0; a < 4; ++a)
        #pragma unroll
        for (int b = 0; b < 4; ++b) acc2[a][b] = (f32x4)(0.f);
    float psum[4] = {0.f, 0.f, 0.f, 0.f};
    const int jbase = (lane >> 4) * 8;

    #pragma unroll 1
    for (int kt = 0; kt < 8; ++kt) {
        int j0 = kt * 32 + jbase;
        bf16x8 bfr[4];
        #pragma unroll
        for (int nt = 0; nt < 4; ++nt)
            bfr[nt] = *(const bf16x8*)(Wp + ((kt * 4 + nt) * 64 + lane) * 8);
        f32x4 d0 = *(const f32x4*)&dv_l[j0];
        f32x4 d1 = *(const f32x4*)&dv_l[j0 + 4];
        #pragma unroll
        for (int mt = 0; mt < 4; ++mt) {
            int prow = wrow + mt * 16 + (lane & 15);
            bf16x8 mrow = *(const bf16x8*)(Mb + prow * 256 + j0);
            float p[8];
            #pragma unroll
            for (int e = 0; e < 4; ++e) {
                float u = sv4[mt] + d0[e];
                u = fmaxf(u, 0.2f * u);
                p[e] = __expf(u + b2f(mrow[e]) - mB);
                float w = sv4[mt] + d1[e];
                w = fmaxf(w, 0.2f * w);
                p[4 + e] = __expf(w + b2f(mrow[4 + e]) - mB);
            }
            psum[mt] += ((p[0] + p[1]) + (p[2] + p[3])) + ((p[4] + p[5]) + (p[6] + p[7]));
            uint4 upf;
            upf.x = pk2(p[0], p[1]); upf.y = pk2(p[2], p[3]);
            upf.z = pk2(p[4], p[5]); upf.w = pk2(p[6], p[7]);
            bf16x8 pf = *reinterpret_cast<bf16x8*>(&upf);
            #pragma unroll
            for (int nt = 0; nt < 4; ++nt)
                acc2[mt][nt] = __builtin_amdgcn_mfma_f32_16x16x32_bf16(pf, bfr[nt], acc2[mt][nt], 0, 0, 0);
        }
    }
    #pragma unroll
    for (int mt = 0; mt < 4; ++mt) {
        psum[mt] += __shfl_xor(psum[mt], 16);
        psum[mt] += __shfl_xor(psum[mt], 32);
    }

    float part[4] = {0.f, 0.f, 0.f, 0.f};
    #pragma unroll
    for (int mt = 0; mt < 4; ++mt) {
        #pragma unroll
        for (int r = 0; r < 4; ++r) {
            float rs  = __shfl(psum[mt], ((lane >> 4) << 2) + r);
            float inv = 1.0f / rs;
            #pragma unroll
            for (int nt = 0; nt < 4; ++nt) {
                float x = acc2[mt][nt][r] * inv;
                x = (x > 0.f) ? x : expm1f(x);
                part[nt] += x;
            }
        }
    }
    #pragma unroll
    for (int nt = 0; nt < 4; ++nt) {
        part[nt] += __shfl_xor(part[nt], 16);
        part[nt] += __shfl_xor(part[nt], 32);
    }
    if ((lane >> 4) == 0) {
        #pragma unroll
        for (int nt = 0; nt < 4; ++nt) red[wv * 64 + nt * 16 + lane] = part[nt];
    }
    __syncthreads();
    if (tid < 64) {
        float f = (red[tid] + red[64 + tid] + red[128 + tid] + red[192 + tid]) * (1.0f / 256.0f);
        feats[bt * 64 + tid] = f;
        feats_l[tid] = f;
    }
    __syncthreads();
    {
        float a = lbih[tid] + lbhh[tid];
        const float* wp = lWih + tid * 64;
        #pragma unroll
        for (int k4 = 0; k4 < 16; ++k4) {
            f32x4 w = *(const f32x4*)(wp + k4 * 4);
            f32x4 x = *(const f32x4*)&feats_l[k4 * 4];
            a += w[0] * x[0] + w[1] * x[1] + w[2] * x[2] + w[3] * x[3];
        }
        gx[bt * 256 + tid] = a;
    }
}

// ---------- K3: dedicated LSTM. 4 blocks x 64 threads, f16-dot2, no barriers/LDS ----------
// Lane l owns h[l], c[l] and Whh rows {l,64+l,128+l,192+l} as f16 pairs (128 VGPRs).
__global__ __launch_bounds__(64, 1) void k_lstm(
    const float* __restrict__ gx, const float* __restrict__ lWhh,
    float* __restrict__ lout) {
    const int lane = threadIdx.x;
    const int b = blockIdx.x;

    h16x2 wi_[32], wf_[32], wg_[32], wo_[32];
    {
        const float* r0 = lWhh + (size_t)lane * 64;
        const float* r1 = lWhh + (size_t)(64 + lane) * 64;
        const float* r2 = lWhh + (size_t)(128 + lane) * 64;
        const float* r3 = lWhh + (size_t)(192 + lane) * 64;
        #pragma unroll
        for (int q = 0; q < 16; ++q) {
            f32x4 a0 = *(const f32x4*)(r0 + q * 4);
            f32x4 a1 = *(const f32x4*)(r1 + q * 4);
            f32x4 a2 = *(const f32x4*)(r2 + q * 4);
            f32x4 a3 = *(const f32x4*)(r3 + q * 4);
            wi_[2*q]   = __builtin_amdgcn_cvt_pkrtz(a0[0], a0[1]);
            wi_[2*q+1] = __builtin_amdgcn_cvt_pkrtz(a0[2], a0[3]);
            wf_[2*q]   = __builtin_amdgcn_cvt_pkrtz(a1[0], a1[1]);
            wf_[2*q+1] = __builtin_amdgcn_cvt_pkrtz(a1[2], a1[3]);
            wg_[2*q]   = __builtin_amdgcn_cvt_pkrtz(a2[0], a2[1]);
            wg_[2*q+1] = __builtin_amdgcn_cvt_pkrtz(a2[2], a2[3]);
            wo_[2*q]   = __builtin_amdgcn_cvt_pkrtz(a3[0], a3[1]);
            wo_[2*q+1] = __builtin_amdgcn_cvt_pkrtz(a3[2], a3[3]);
        }
    }
    const float* gxb = gx + (size_t)b * 36864;
    float* lop = lout + (size_t)b * 9216;
    float c_s = 0.f, h = 0.f;
    float gA0 = gxb[lane],       gA1 = gxb[64 + lane],
          gA2 = gxb[128 + lane], gA3 = gxb[192 + lane];
    float gB0 = gxb[256 + lane], gB1 = gxb[320 + lane],
          gB2 = gxb[384 + lane], gB3 = gxb[448 + lane];

    #define LSTM1W_STEP(T, G0, G1, G2, G3)                                       \
    {                                                                            \
        int t_ = (T);                                                            \
        float ai = (G0), af = (G1), ag = (G2), ao = (G3);                        \
        if (t_ + 2 < 144) {                                                      \
            const float* pf_ = gxb + (t_ + 2) * 256;                             \
            G0 = pf_[lane];       G1 = pf_[64 + lane];                           \
            G2 = pf_[128 + lane]; G3 = pf_[192 + lane];                          \
        }                                                                        \
        float hsw_ = __shfl_xor(h, 1);                                           \
        unsigned hpu_ = h2u(__builtin_amdgcn_cvt_pkrtz(h, hsw_));                \
        _Pragma("unroll")                                                        \
        for (int q = 0; q < 32; ++q) {                                           \
            h16x2 hv_ = u2h((unsigned)__builtin_amdgcn_readlane((int)hpu_, 2 * q)); \
            ai = DOT2(wi_[q], hv_, ai);                                          \
            af = DOT2(wf_[q], hv_, af);                                          \
            ag = DOT2(wg_[q], hv_, ag);                                          \
            ao = DOT2(wo_[q], hv_, ao);                                          \
        }                                                                        \
        c_s = sigf(af) * c_s + sigf(ai) * tanh_(ag);                             \
        h   = sigf(ao) * tanh_(c_s);                                             \
        lop[t_ * 64 + lane] = h;                                                 \
    }

    for (int tt = 0; tt < 72; ++tt) {
        LSTM1W_STEP(2 * tt,     gA0, gA1, gA2, gA3)
        LSTM1W_STEP(2 * tt + 1, gB0, gB1, gB2, gB3)
    }
    #undef LSTM1W_STEP
}

// ---------- K4: ctxL (blocks 0-3, lout staged to LDS) + GRU/ctxS (blocks 4-19) ----------
__global__ __launch_bounds__(256) void k_ctx2(
    const float* __restrict__ lout, const float* __restrict__ aLW,
    const float* __restrict__ aLb, const float* __restrict__ aLv,
    const float* __restrict__ feats, const float* __restrict__ gWih,
    const float* __restrict__ gWhh, const float* __restrict__ gbih,
    const float* __restrict__ gbhh, const float* __restrict__ aSW,
    const float* __restrict__ aSb, const float* __restrict__ aSv,
    float* __restrict__ ctxL, float* __restrict__ ctxS) {
    __shared__ __align__(16) float smem[9504];
    int tid = threadIdx.x;
    if (blockIdx.x < 4) {
        int b = blockIdx.x;
        int wv = tid >> 6, lane = tid & 63;
        float* Hl = smem;               // [144][64]
        float* sc = smem + 9216;        // [144]
        float* al = smem + 9360;        // [144]
        for (int i = tid; i < 9216; i += 256) Hl[i] = lout[b * 9216 + i];
        float wcol[64];
        #pragma unroll
        for (int k = 0; k < 64; ++k) wcol[k] = aLW[k * 64 + lane];
        float bb = aLb[lane], vv = aLv[lane];
        __syncthreads();
        for (int g = 0; g < 36; ++g) {
            int t = g * 4 + wv;
            float acc = bb;
            #pragma unroll
            for (int q = 0; q < 16; ++q) {
                f32x4 h4 = *(const f32x4*)&Hl[t * 64 + q * 4];
                acc += wcol[q * 4 + 0] * h4[0] + wcol[q * 4 + 1] * h4[1]
                     + wcol[q * 4 + 2] * h4[2] + wcol[q * 4 + 3] * h4[3];
            }
            float p = tanh_(acc) * vv;
            #pragma unroll
            for (int m = 1; m < 64; m <<= 1) p += __shfl_xor(p, m);
            if (lane == 0) sc[t] = p;
        }
        __syncthreads();
        float mx = -3e38f;
        for (int t2 = 0; t2 < 144; ++t2) mx = fmaxf(mx, sc[t2]);
        float ss = 0.f;
        for (int t2 = 0; t2 < 144; ++t2) ss += __expf(sc[t2] - mx);
        float inv = 1.f / ss;
        if (tid < 144) al[tid] = __expf(sc[tid] - mx) * inv;
        __syncthreads();
        if (tid < 64) {
            float acc = 0.f;
            for (int t2 = 0; t2 < 144; ++t2) acc += al[t2] * Hl[t2 * 64 + tid];
            ctxL[b * 64 + tid] = acc;
        }
    } else {
        int bi_ = blockIdx.x - 4;
        int b = bi_ >> 2, c2 = bi_ & 3;
        float* hvg = smem;
        float* xvg = smem + 64;
        float* gxl = smem + 128;
        float* ghl = smem + 320;
        float* hst = smem + 512;        // [9][64]
        float wi[64], wh[64], bi = 0.f, bh = 0.f, h_s = 0.f;
        if (tid < 192) {
            #pragma unroll
            for (int q = 0; q < 16; ++q) {
                *(f32x4*)&wi[q * 4] = *(const f32x4*)&gWih[(size_t)(c2 * 192 + tid) * 64 + q * 4];
                *(f32x4*)&wh[q * 4] = *(const f32x4*)&gWhh[(size_t)(c2 * 192 + tid) * 64 + q * 4];
            }
            bi = gbih[c2 * 192 + tid];
            bh = gbhh[c2 * 192 + tid];
        }
        if (tid < 64) hvg[tid] = 0.f;
        __syncthreads();
        for (int s = 0; s < 9; ++s) {
            int t = 108 + c2 * 9 + s;
            if (tid < 64) xvg[tid] = feats[(b * 144 + t) * 64 + tid];
            __syncthreads();
            if (tid < 192) {
                float ax = bi, ah = bh;
                float a0 = 0.f, a1 = 0.f, b0 = 0.f, b1 = 0.f;
                #pragma unroll
                for (int k = 0; k < 64; k += 2) {
                    a0 += wi[k] * xvg[k];     a1 += wi[k + 1] * xvg[k + 1];
                    b0 += wh[k] * hvg[k];     b1 += wh[k + 1] * hvg[k + 1];
                }
                gxl[tid] = ax + a0 + a1; ghl[tid] = ah + b0 + b1;
            }
            __syncthreads();
            if (tid < 64) {
                float xr = gxl[tid], xz = gxl[64 + tid], xn = gxl[128 + tid];
                float hr = ghl[tid], hz = ghl[64 + tid], hn = ghl[128 + tid];
                float rr = sigf(xr + hr), zz = sigf(xz + hz);
                float nn = tanh_(xn + rr * hn);
                h_s = (1.f - zz) * nn + zz * h_s;
                hvg[tid] = h_s;
                hst[s * 64 + tid] = h_s;
            }
            __syncthreads();
        }
        if (tid < 64) {
            int lane = tid;
            const float* Wc = aSW + c2 * 4096;
            float wcol[64];
            #pragma unroll
            for (int k = 0; k < 64; ++k) wcol[k] = Wc[k * 64 + lane];
            float bb = aSb[c2 * 64 + lane], vv = aSv[c2 * 64 + lane];
            float sv[9];
            #pragma unroll 1
            for (int s = 0; s < 9; ++s) {
                float acc = bb;
                #pragma unroll
                for (int q = 0; q < 16; ++q) {
                    f32x4 h4 = *(const f32x4*)&hst[s * 64 + q * 4];
                    acc += wcol[q * 4 + 0] * h4[0] + wcol[q * 4 + 1] * h4[1]
                         + wcol[q * 4 + 2] * h4[2] + wcol[q * 4 + 3] * h4[3];
                }
                float p = tanh_(acc) * vv;
                #pragma unroll
                for (int m = 1; m < 64; m <<= 1) p += __shfl_xor(p, m);
                sv[s] = p;
            }
            float mx = -3e38f;
            #pragma unroll
            for (int s = 0; s < 9; ++s) mx = fmaxf(mx, sv[s]);
            float ss = 0.f;
            #pragma unroll
            for (int s = 0; s < 9; ++s) { sv[s] = __expf(sv[s] - mx); ss += sv[s]; }
            float inv = 1.f / ss;
            float acc = 0.f;
            #pragma unroll
            for (int s = 0; s < 9; ++s) acc += sv[s] * inv * hst[s * 64 + lane];
            ctxS[(b * 4 + c2) * 64 + lane] = acc;
        }
    }
}

// ---------- K5: concat + lin1 + relu ----------
__global__ __launch_bounds__(512) void k_lin1(
    const float* __restrict__ ctxL, const float* __restrict__ ctxS,
    const float* __restrict__ W, const float* __restrict__ bb,
    float* __restrict__ h1) {
    int tid = threadIdx.x;
    __shared__ __align__(16) float fu[4 * 320];
    for (int c = tid; c < 1280; c += 512) {
        int b2 = c / 320, k = c % 320;
        fu[c] = (k < 64) ? ctxL[b2 * 64 + k] : ctxS[b2 * 256 + (k - 64)];
    }
    __syncthreads();
    int b = tid >> 7, r = tid & 127;
    float acc = bb[r];
    #pragma unroll 4
    for (int k4 = 0; k4 < 80; ++k4) {
        f32x4 w = *(const f32x4*)&W[r * 320 + k4 * 4];
        f32x4 x = *(const f32x4*)&fu[b * 320 + k4 * 4];
        acc += w[0] * x[0] + w[1] * x[1] + w[2] * x[2] + w[3] * x[3];
    }
    h1[b * 128 + r] = fmaxf(acc, 0.f);
}

// ---------- K6: lin2, streaming W. 1024 blocks, 4 lanes/row ----------
__global__ __launch_bounds__(256) void k_lin2(
    const float* __restrict__ h1, const float* __restrict__ W,
    const float* __restrict__ bb, float* __restrict__ h2) {
    __shared__ __align__(16) float h1l[512];
    int tid = threadIdx.x, blk = blockIdx.x;
    for (int c = tid; c < 512; c += 256) h1l[c] = h1[c];
    __syncthreads();
    int r = blk * 64 + (tid >> 2);
    int q = tid & 3;
    const float* wp = W + (size_t)r * 128 + q * 32;
    float a0 = 0.f, a1 = 0.f, a2 = 0.f, a3 = 0.f;
    #pragma unroll
    for (int i = 0; i < 8; ++i) {
        f32x4 w  = *(const f32x4*)(wp + i * 4);
        f32x4 x0 = *(const f32x4*)&h1l[q * 32 + i * 4];
        f32x4 x1 = *(const f32x4*)&h1l[128 + q * 32 + i * 4];
        f32x4 x2 = *(const f32x4*)&h1l[256 + q * 32 + i * 4];
        f32x4 x3 = *(const f32x4*)&h1l[384 + q * 32 + i * 4];
        a0 += w[0] * x0[0] + w[1] * x0[1] + w[2] * x0[2] + w[3] * x0[3];
        a1 += w[0] * x1[0] + w[1] * x1[1] + w[2] * x1[2] + w[3] * x1[3];
        a2 += w[0] * x2[0] + w[1] * x2[1] + w[2] * x2[2] + w[3] * x2[3];
        a3 += w[0] * x3[0] + w[1] * x3[1] + w[2] * x3[2] + w[3] * x3[3];
    }
    a0 += __shfl_xor(a0, 1); a0 += __shfl_xor(a0, 2);
    a1 += __shfl_xor(a1, 1); a1 += __shfl_xor(a1, 2);
    a2 += __shfl_xor(a2, 1); a2 += __shfl_xor(a2, 2);
    a3 += __shfl_xor(a3, 1); a3 += __shfl_xor(a3, 2);
    if (q == 0) {
        float bv = bb[r];
        h2[r]             = a0 + bv;
        h2[65536 + r]     = a1 + bv;
        h2[2 * 65536 + r] = a2 + bv;
        h2[3 * 65536 + r] = a3 + bv;
    }
}

// ---------- K7: 3x3 SAME conv + bias + softplus ----------
__global__ __launch_bounds__(256) void k_conv(
    const float* __restrict__ h2, const float* __restrict__ ck,
    const float* __restrict__ cb, float* __restrict__ out) {
    int x = threadIdx.x;
    int b = blockIdx.x >> 8, y = blockIdx.x & 255;
    float kk[9];
    #pragma unroll
    for (int i = 0; i < 9; ++i) kk[i] = ck[i];
    const float* base = h2 + b * 65536;
    float acc = cb[0];
    #pragma unroll
    for (int dy = -1; dy <= 1; ++dy) {
        int yy = y + dy;
        if (yy < 0 || yy > 255) continue;
        #pragma unroll
        for (int dx = -1; dx <= 1; ++dx) {
            int xx = x + dx;
            if (xx < 0 || xx > 255) continue;
            acc += base[yy * 256 + xx] * kk[(dy + 1) * 3 + (dx + 1)];
        }
    }
    float r = (acc > 20.f) ? acc : log1pf(__expf(acc));
    out[b * 65536 + y * 256 + x] = r;
}

extern "C" void kernel_launch(void* const* d_in, const int* in_sizes, int n_in,
                              void* d_out, int out_size, void* d_ws, size_t ws_size,
                              hipStream_t stream) {
    const float* seg   = (const float*)d_in[0];
    const float* adj   = (const float*)d_in[1];
    const float* dist  = (const float*)d_in[2];
    const float* W_gat = (const float*)d_in[3];
    const float* a_src = (const float*)d_in[4];
    const float* a_dst = (const float*)d_in[5];
    const float* lWih  = (const float*)d_in[6];
    const float* lWhh  = (const float*)d_in[7];
    const float* lbih  = (const float*)d_in[8];
    const float* lbhh  = (const float*)d_in[9];
    const float* aLW   = (const float*)d_in[10];
    const float* aLb   = (const float*)d_in[11];
    const float* aLv   = (const float*)d_in[12];
    const float* gWih  = (const float*)d_in[13];
    const float* gWhh  = (const float*)d_in[14];
    const float* gbih  = (const float*)d_in[15];
    const float* gbhh  = (const float*)d_in[16];
    const float* aSW   = (const float*)d_in[17];
    const float* aSb   = (const float*)d_in[18];
    const float* aSv   = (const float*)d_in[19];
    const float* l1W   = (const float*)d_in[20];
    const float* l1b   = (const float*)d_in[21];
    const float* l2W   = (const float*)d_in[22];
    const float* l2b   = (const float*)d_in[23];
    const float* ck    = (const float*)d_in[24];
    const float* cb    = (const float*)d_in[25];
    float* out = (float*)d_out;

    float* ws = (float*)d_ws;
    unsigned short* Mb  = (unsigned short*)ws;                    // 65536 ush
    unsigned short* Wt  = (unsigned short*)(ws + 32768);          // 16384 ush
    float* svec  = ws + 40960;                                    // 147456
    float* dvec  = svec + 147456;                                 // 147456
    float* smaxp = dvec + 147456;                                 // 2304
    float* dmaxp = smaxp + 2304;                                  // 2304
    unsigned short* WhT = (unsigned short*)(dmaxp + 2304);        // 9437184 ush
    float* feats = dmaxp + 2304 + 4718592;                        // 36864
    float* gx    = feats + 36864;                                 // 147456
    float* lout  = gx + 147456;                                   // 36864
    float* ctxL  = lout + 36864;                                  // 256
    float* ctxS  = ctxL + 256;                                    // 1024
    float* h1    = ctxS + 1024;                                   // 512
    float* h2    = h1 + 512;                                      // 262144

    k_prep<<<257, 256, 0, stream>>>(adj, dist, W_gat, Mb, Wt);
    k_gatA<<<2304, 256, 0, stream>>>(seg, Wt, a_src, a_dst, WhT, svec, dvec, smaxp, dmaxp);
    k_gatBF<<<576, 256, 0, stream>>>(WhT, svec, dvec, smaxp, dmaxp, Mb, lWih, lbih, lbhh, feats, gx);
    k_lstm<<<4, 64, 0, stream>>>(gx, lWhh, lout);
    k_ctx2<<<20, 256, 0, stream>>>(lout, aLW, aLb, aLv, feats, gWih, gWhh, gbih, gbhh,
                                   aSW, aSb, aSv, ctxL, ctxS);
    k_lin1<<<1, 512, 0, stream>>>(ctxL, ctxS, l1W, l1b, h1);
    k_lin2<<<1024, 256, 0, stream>>>(h1, l2W, l2b, h2);
    k_conv<<<1024, 256, 0, stream>>>(h2, ck, cb, out);
}

// Round 13
// 249.726 us; speedup vs baseline: 1.0030x; 1.0030x over previous
//
#include <hip/hip_runtime.h>
#include <hip/hip_bf16.h>
#include <cstddef>

// B=4, T=144, N=256, H=64, NC=4, CH=9, BT=576.
// Chain: prep -> gatA -> gatBF -> k_lstm (64-thr blocks, f16-dot2, weights as whole
// ext-vector SSA values so the allocator cannot demote them) -> k_ctx2 -> lin1 -> lin2 -> conv.
// (~85 us of dur_us is an irreducible harness ws-fill.)

typedef __attribute__((ext_vector_type(8))) short bf16x8;
typedef __attribute__((ext_vector_type(4))) float f32x4;
typedef __fp16 h16x2 __attribute__((ext_vector_type(2)));
typedef unsigned u32x32 __attribute__((ext_vector_type(32)));   // 32 VGPRs, one SSA value

#if __has_builtin(__builtin_amdgcn_fdot2)
#define DOT2(a, b, c) __builtin_amdgcn_fdot2((a), (b), (c), false)
#else
#define DOT2(a, b, c) ((c) + (float)(a)[0] * (float)(b)[0] + (float)(a)[1] * (float)(b)[1])
#endif

__device__ __forceinline__ float rcp_(float x) { return __builtin_amdgcn_rcpf(x); }
__device__ __forceinline__ float sigf(float x) { return rcp_(1.0f + __expf(-x)); }
__device__ __forceinline__ float tanh_(float x) {
    x = fminf(fmaxf(x, -15.f), 15.f);
    float e = __expf(2.f * x);
    return (e - 1.f) * rcp_(e + 1.f);
}
__device__ __forceinline__ unsigned short f2b(float f) {
    unsigned u = __float_as_uint(f);
    u += 0x7FFFu + ((u >> 16) & 1u);
    return (unsigned short)(u >> 16);
}
__device__ __forceinline__ unsigned pk2(float lo, float hi) {
    __hip_bfloat162 h = __float22bfloat162_rn(float2{lo, hi});
    return *reinterpret_cast<unsigned*>(&h);
}
__device__ __forceinline__ float b2f(short s) {
    return __uint_as_float(((unsigned)(unsigned short)s) << 16);
}
__device__ __forceinline__ unsigned h2u2(h16x2 v) { return __builtin_bit_cast(unsigned, v); }
__device__ __forceinline__ h16x2 u2h2(unsigned u) { return __builtin_bit_cast(h16x2, u); }

// ---------- K1: Mb bf16 mask ; Wt bf16 [64 cols][256 k] ----------
__global__ void k_prep(const float* __restrict__ adj, const float* __restrict__ dist,
                       const float* __restrict__ W_gat,
                       unsigned short* __restrict__ Mb, unsigned short* __restrict__ Wt) {
    int blk = blockIdx.x, tid = threadIdx.x;
    if (blk < 256) {
        int i = blk * 256 + tid;
        Mb[i] = f2b((adj[i] > 0.f) ? -dist[i] : -1e9f);
    } else {
        for (int it = 0; it < 64; ++it) {
            int e = it * 256 + tid;
            int k = e >> 6, c = e & 63;
            Wt[c * 256 + k] = f2b(W_gat[e]);
        }
    }
}

// ---------- K2a: Wh GEMM. 2304 blocks (bt = blk>>2, sub = blk&3), 64 rows each ----------
__global__ __launch_bounds__(256, 6) void k_gatA(
    const float* __restrict__ seg, const unsigned short* __restrict__ Wt,
    const float* __restrict__ a_src, const float* __restrict__ a_dst,
    unsigned short* __restrict__ WhT, float* __restrict__ svec, float* __restrict__ dvec,
    float* __restrict__ smaxp, float* __restrict__ dmaxp) {
    __shared__ __align__(16) short A_s[64 * 64];
    __shared__ float red[8];

    const int tid  = threadIdx.x;
    const int lane = tid & 63;
    const int wv   = tid >> 6;
    const int blk  = blockIdx.x;
    const int bt   = blk >> 2;
    const int sub  = blk & 3;
    const float* __restrict__ segp = seg + (size_t)bt * 65536 + sub * 64 * 256;

    f32x4 acc[4];
    #pragma unroll
    for (int n = 0; n < 4; ++n) acc[n] = (f32x4)(0.f);

    for (int kc = 0; kc < 4; ++kc) {
        #pragma unroll
        for (int it = 0; it < 2; ++it) {
            int unit = it * 256 + tid;
            int row = unit >> 3, u = unit & 7;
            const float* g = segp + row * 256 + kc * 64 + u * 8;
            f32x4 v0 = *(const f32x4*)g;
            f32x4 v1 = *(const f32x4*)(g + 4);
            uint4 pk;
            pk.x = pk2(v0[0], v0[1]); pk.y = pk2(v0[2], v0[3]);
            pk.z = pk2(v1[0], v1[1]); pk.w = pk2(v1[2], v1[3]);
            *(uint4*)&A_s[(row * 8 + (u ^ (row & 7))) * 8] = pk;
        }
        bf16x8 bfr[2][4];
        #pragma unroll
        for (int kt2 = 0; kt2 < 2; ++kt2) {
            int ku = kt2 * 4 + (lane >> 4);
            #pragma unroll
            for (int nt = 0; nt < 4; ++nt) {
                int col = nt * 16 + (lane & 15);
                bfr[kt2][nt] = *(const bf16x8*)(Wt + col * 256 + kc * 64 + ku * 8);
            }
        }
        __syncthreads();
        int arow = wv * 16 + (lane & 15);
        #pragma unroll
        for (int kt2 = 0; kt2 < 2; ++kt2) {
            int ku = kt2 * 4 + (lane >> 4);
            bf16x8 afr = *(const bf16x8*)&A_s[(arow * 8 + (ku ^ (arow & 7))) * 8];
            #pragma unroll
            for (int nt = 0; nt < 4; ++nt)
                acc[nt] = __builtin_amdgcn_mfma_f32_16x16x32_bf16(afr, bfr[kt2][nt], acc[nt], 0, 0, 0);
        }
        __syncthreads();
    }

    float asv[4], adv[4];
    #pragma unroll
    for (int nt = 0; nt < 4; ++nt) {
        asv[nt] = a_src[nt * 16 + (lane & 15)];
        adv[nt] = a_dst[nt * 16 + (lane & 15)];
    }
    float mxs = -3e38f, mxd = -3e38f;
    int rowbase = sub * 64 + wv * 16;
    #pragma unroll
    for (int r = 0; r < 4; ++r) {
        float ps = acc[0][r] * asv[0] + acc[1][r] * asv[1] + acc[2][r] * asv[2] + acc[3][r] * asv[3];
        float pd = acc[0][r] * adv[0] + acc[1][r] * adv[1] + acc[2][r] * adv[2] + acc[3][r] * adv[3];
        #pragma unroll
        for (int m = 1; m < 16; m <<= 1) { ps += __shfl_xor(ps, m); pd += __shfl_xor(pd, m); }
        if ((lane & 15) == 0) {
            int row = rowbase + (lane >> 4) * 4 + r;
            svec[bt * 256 + row] = ps;
            dvec[bt * 256 + row] = pd;
        }
        mxs = fmaxf(mxs, ps); mxd = fmaxf(mxd, pd);
    }
    mxs = fmaxf(mxs, __shfl_xor(mxs, 16)); mxs = fmaxf(mxs, __shfl_xor(mxs, 32));
    mxd = fmaxf(mxd, __shfl_xor(mxd, 16)); mxd = fmaxf(mxd, __shfl_xor(mxd, 32));
    if (lane == 0) { red[wv] = mxs; red[4 + wv] = mxd; }

    {
        int c = lane & 15, q = lane >> 4;
        int kt2  = wv >> 1;
        int oct  = (wv & 1) * 2 + (q >> 1);
        int laneP = oct * 16 + c;
        int e0b  = (q & 1) * 8;
        #pragma unroll
        for (int nt = 0; nt < 4; ++nt) {
            uint2 pk4;
            pk4.x = pk2(acc[nt][0], acc[nt][1]);
            pk4.y = pk2(acc[nt][2], acc[nt][3]);
            *(uint2*)((char*)A_s + (((kt2 * 4 + nt) * 64 + laneP) * 16 + e0b)) = pk4;
        }
    }
    __syncthreads();
    {
        const uint4* Fs = (const uint4*)A_s;
        uint4* Gd = (uint4*)(WhT + (size_t)bt * 16384 + sub * 4096);
        Gd[tid] = Fs[tid];
        Gd[256 + tid] = Fs[256 + tid];
    }
    if (tid == 0) {
        smaxp[blk] = fmaxf(fmaxf(red[0], red[1]), fmaxf(red[2], red[3]));
        dmaxp[blk] = fmaxf(fmaxf(red[4], red[5]), fmaxf(red[6], red[7]));
    }
}

// ---------- K2b: fused exp+PV+normalize+elu+mean+gx. One block per bt (576 blocks) ----------
__global__ __launch_bounds__(256, 4) void k_gatBF(
    const unsigned short* __restrict__ WhT, const float* __restrict__ svec,
    const float* __restrict__ dvec, const float* __restrict__ smaxp,
    const float* __restrict__ dmaxp, const unsigned short* __restrict__ Mb,
    const float* __restrict__ lWih, const float* __restrict__ lbih,
    const float* __restrict__ lbhh, float* __restrict__ feats, float* __restrict__ gx) {
    __shared__ __align__(16) float dv_l[256];
    __shared__ float red[256];
    __shared__ __align__(16) float feats_l[64];

    const int tid  = threadIdx.x;
    const int lane = tid & 63;
    const int wv   = tid >> 6;
    const int wrow = wv * 64;
    const int bt   = blockIdx.x;
    const unsigned short* __restrict__ Wp = WhT + (size_t)bt * 16384;

    dv_l[tid] = dvec[bt * 256 + tid];
    float mB;
    {
        float ms = fmaxf(fmaxf(smaxp[bt * 4], smaxp[bt * 4 + 1]),
                         fmaxf(smaxp[bt * 4 + 2], smaxp[bt * 4 + 3]));
        float md = fmaxf(fmaxf(dmaxp[bt * 4], dmaxp[bt * 4 + 1]),
                         fmaxf(dmaxp[bt * 4 + 2], dmaxp[bt * 4 + 3]));
        float x = ms + md;
        mB = fmaxf(x, 0.2f * x);
    }
    float sv4[4];
    #pragma unroll
    for (int mt = 0; mt < 4; ++mt) sv4[mt] = svec[bt * 256 + wrow + mt * 16 + (lane & 15)];
    __syncthreads();

    f32x4 acc2[4][4];
    #pragma unroll
    for (int a = 0; a < 4; ++a)
        #pragma unroll
        for (int b = 0; b < 4; ++b) acc2[a][b] = (f32x4)(0.f);
    float psum[4] = {0.f, 0.f, 0.f, 0.f};
    const int jbase = (lane >> 4) * 8;

    #pragma unroll 1
    for (int kt = 0; kt < 8; ++kt) {
        int j0 = kt * 32 + jbase;
        bf16x8 bfr[4];
        #pragma unroll
        for (int nt = 0; nt < 4; ++nt)
            bfr[nt] = *(const bf16x8*)(Wp + ((kt * 4 + nt) * 64 + lane) * 8);
        f32x4 d0 = *(const f32x4*)&dv_l[j0];
        f32x4 d1 = *(const f32x4*)&dv_l[j0 + 4];
        #pragma unroll
        for (int mt = 0; mt < 4; ++mt) {
            int prow = wrow + mt * 16 + (lane & 15);
            bf16x8 mrow = *(const bf16x8*)(Mb + prow * 256 + j0);
            float p[8];
            #pragma unroll
            for (int e = 0; e < 4; ++e) {
                float u = sv4[mt] + d0[e];
                u = fmaxf(u, 0.2f * u);
                p[e] = __expf(u + b2f(mrow[e]) - mB);
                float w = sv4[mt] + d1[e];
                w = fmaxf(w, 0.2f * w);
                p[4 + e] = __expf(w + b2f(mrow[4 + e]) - mB);
            }
            psum[mt] += ((p[0] + p[1]) + (p[2] + p[3])) + ((p[4] + p[5]) + (p[6] + p[7]));
            uint4 upf;
            upf.x = pk2(p[0], p[1]); upf.y = pk2(p[2], p[3]);
            upf.z = pk2(p[4], p[5]); upf.w = pk2(p[6], p[7]);
            bf16x8 pf = *reinterpret_cast<bf16x8*>(&upf);
            #pragma unroll
            for (int nt = 0; nt < 4; ++nt)
                acc2[mt][nt] = __builtin_amdgcn_mfma_f32_16x16x32_bf16(pf, bfr[nt], acc2[mt][nt], 0, 0, 0);
        }
    }
    #pragma unroll
    for (int mt = 0; mt < 4; ++mt) {
        psum[mt] += __shfl_xor(psum[mt], 16);
        psum[mt] += __shfl_xor(psum[mt], 32);
    }

    float part[4] = {0.f, 0.f, 0.f, 0.f};
    #pragma unroll
    for (int mt = 0; mt < 4; ++mt) {
        #pragma unroll
        for (int r = 0; r < 4; ++r) {
            float rs  = __shfl(psum[mt], ((lane >> 4) << 2) + r);
            float inv = 1.0f / rs;
            #pragma unroll
            for (int nt = 0; nt < 4; ++nt) {
                float x = acc2[mt][nt][r] * inv;
                x = (x > 0.f) ? x : expm1f(x);
                part[nt] += x;
            }
        }
    }
    #pragma unroll
    for (int nt = 0; nt < 4; ++nt) {
        part[nt] += __shfl_xor(part[nt], 16);
        part[nt] += __shfl_xor(part[nt], 32);
    }
    if ((lane >> 4) == 0) {
        #pragma unroll
        for (int nt = 0; nt < 4; ++nt) red[wv * 64 + nt * 16 + lane] = part[nt];
    }
    __syncthreads();
    if (tid < 64) {
        float f = (red[tid] + red[64 + tid] + red[128 + tid] + red[192 + tid]) * (1.0f / 256.0f);
        feats[bt * 64 + tid] = f;
        feats_l[tid] = f;
    }
    __syncthreads();
    {
        float a = lbih[tid] + lbhh[tid];
        const float* wp = lWih + tid * 64;
        #pragma unroll
        for (int k4 = 0; k4 < 16; ++k4) {
            f32x4 w = *(const f32x4*)(wp + k4 * 4);
            f32x4 x = *(const f32x4*)&feats_l[k4 * 4];
            a += w[0] * x[0] + w[1] * x[1] + w[2] * x[2] + w[3] * x[3];
        }
        gx[bt * 256 + tid] = a;
    }
}

// ---------- K3: dedicated LSTM. 4 blocks x 64 threads. Weights = 4 whole u32x32 vectors ----------
__global__ __launch_bounds__(64, 1) void k_lstm(
    const float* __restrict__ gx, const float* __restrict__ lWhh,
    float* __restrict__ lout) {
    const int lane = threadIdx.x;
    const int b = blockIdx.x;

    u32x32 wiv, wfv, wgv, wov;     // each a single 32-VGPR SSA value (128 total)
    {
        const float* r0 = lWhh + (size_t)lane * 64;
        const float* r1 = lWhh + (size_t)(64 + lane) * 64;
        const float* r2 = lWhh + (size_t)(128 + lane) * 64;
        const float* r3 = lWhh + (size_t)(192 + lane) * 64;
        #pragma unroll
        for (int q = 0; q < 16; ++q) {
            f32x4 a0 = *(const f32x4*)(r0 + q * 4);
            f32x4 a1 = *(const f32x4*)(r1 + q * 4);
            f32x4 a2 = *(const f32x4*)(r2 + q * 4);
            f32x4 a3 = *(const f32x4*)(r3 + q * 4);
            wiv[2*q]   = h2u2(__builtin_amdgcn_cvt_pkrtz(a0[0], a0[1]));
            wiv[2*q+1] = h2u2(__builtin_amdgcn_cvt_pkrtz(a0[2], a0[3]));
            wfv[2*q]   = h2u2(__builtin_amdgcn_cvt_pkrtz(a1[0], a1[1]));
            wfv[2*q+1] = h2u2(__builtin_amdgcn_cvt_pkrtz(a1[2], a1[3]));
            wgv[2*q]   = h2u2(__builtin_amdgcn_cvt_pkrtz(a2[0], a2[1]));
            wgv[2*q+1] = h2u2(__builtin_amdgcn_cvt_pkrtz(a2[2], a2[3]));
            wov[2*q]   = h2u2(__builtin_amdgcn_cvt_pkrtz(a3[0], a3[1]));
            wov[2*q+1] = h2u2(__builtin_amdgcn_cvt_pkrtz(a3[2], a3[3]));
        }
    }
    const float* gxb = gx + (size_t)b * 36864;
    float* lop = lout + (size_t)b * 9216;
    float c_s = 0.f, h = 0.f;
    float gA0 = gxb[lane],       gA1 = gxb[64 + lane],
          gA2 = gxb[128 + lane], gA3 = gxb[192 + lane];
    float gB0 = gxb[256 + lane], gB1 = gxb[320 + lane],
          gB2 = gxb[384 + lane], gB3 = gxb[448 + lane];

    #define LSTM1W_STEP(T, G0, G1, G2, G3)                                       \
    {                                                                            \
        int t_ = (T);                                                            \
        float ai = (G0), af = (G1), ag = (G2), ao = (G3);                        \
        if (t_ + 2 < 144) {                                                      \
            const float* pf_ = gxb + (t_ + 2) * 256;                             \
            G0 = pf_[lane];       G1 = pf_[64 + lane];                           \
            G2 = pf_[128 + lane]; G3 = pf_[192 + lane];                          \
        }                                                                        \
        float hsw_ = __shfl_xor(h, 1);                                           \
        unsigned hpu_ = h2u2(__builtin_amdgcn_cvt_pkrtz(h, hsw_));               \
        _Pragma("unroll")                                                        \
        for (int q = 0; q < 32; ++q) {                                           \
            h16x2 hv_ = u2h2((unsigned)__builtin_amdgcn_readlane((int)hpu_, 2 * q)); \
            ai = DOT2(u2h2(wiv[q]), hv_, ai);                                    \
            af = DOT2(u2h2(wfv[q]), hv_, af);                                    \
            ag = DOT2(u2h2(wgv[q]), hv_, ag);                                    \
            ao = DOT2(u2h2(wov[q]), hv_, ao);                                    \
        }                                                                        \
        c_s = sigf(af) * c_s + sigf(ai) * tanh_(ag);                             \
        h   = sigf(ao) * tanh_(c_s);                                             \
        lop[t_ * 64 + lane] = h;                                                 \
    }

    for (int tt = 0; tt < 72; ++tt) {
        LSTM1W_STEP(2 * tt,     gA0, gA1, gA2, gA3)
        LSTM1W_STEP(2 * tt + 1, gB0, gB1, gB2, gB3)
    }
    #undef LSTM1W_STEP
}

// ---------- K4: ctxL (blocks 0-3, lout staged to LDS) + GRU/ctxS (blocks 4-19) ----------
__global__ __launch_bounds__(256) void k_ctx2(
    const float* __restrict__ lout, const float* __restrict__ aLW,
    const float* __restrict__ aLb, const float* __restrict__ aLv,
    const float* __restrict__ feats, const float* __restrict__ gWih,
    const float* __restrict__ gWhh, const float* __restrict__ gbih,
    const float* __restrict__ gbhh, const float* __restrict__ aSW,
    const float* __restrict__ aSb, const float* __restrict__ aSv,
    float* __restrict__ ctxL, float* __restrict__ ctxS) {
    __shared__ __align__(16) float smem[9504];
    int tid = threadIdx.x;
    if (blockIdx.x < 4) {
        int b = blockIdx.x;
        int wv = tid >> 6, lane = tid & 63;
        float* Hl = smem;               // [144][64]
        float* sc = smem + 9216;        // [144]
        float* al = smem + 9360;        // [144]
        for (int i = tid; i < 9216; i += 256) Hl[i] = lout[b * 9216 + i];
        float wcol[64];
        #pragma unroll
        for (int k = 0; k < 64; ++k) wcol[k] = aLW[k * 64 + lane];
        float bb = aLb[lane], vv = aLv[lane];
        __syncthreads();
        for (int g = 0; g < 36; ++g) {
            int t = g * 4 + wv;
            float acc = bb;
            #pragma unroll
            for (int q = 0; q < 16; ++q) {
                f32x4 h4 = *(const f32x4*)&Hl[t * 64 + q * 4];
                acc += wcol[q * 4 + 0] * h4[0] + wcol[q * 4 + 1] * h4[1]
                     + wcol[q * 4 + 2] * h4[2] + wcol[q * 4 + 3] * h4[3];
            }
            float p = tanh_(acc) * vv;
            #pragma unroll
            for (int m = 1; m < 64; m <<= 1) p += __shfl_xor(p, m);
            if (lane == 0) sc[t] = p;
        }
        __syncthreads();
        float mx = -3e38f;
        for (int t2 = 0; t2 < 144; ++t2) mx = fmaxf(mx, sc[t2]);
        float ss = 0.f;
        for (int t2 = 0; t2 < 144; ++t2) ss += __expf(sc[t2] - mx);
        float inv = 1.f / ss;
        if (tid < 144) al[tid] = __expf(sc[tid] - mx) * inv;
        __syncthreads();
        if (tid < 64) {
            float acc = 0.f;
            for (int t2 = 0; t2 < 144; ++t2) acc += al[t2] * Hl[t2 * 64 + tid];
            ctxL[b * 64 + tid] = acc;
        }
    } else {
        int bi_ = blockIdx.x - 4;
        int b = bi_ >> 2, c2 = bi_ & 3;
        float* hvg = smem;
        float* xvg = smem + 64;
        float* gxl = smem + 128;
        float* ghl = smem + 320;
        float* hst = smem + 512;        // [9][64]
        float wi[64], wh[64], bi = 0.f, bh = 0.f, h_s = 0.f;
        if (tid < 192) {
            #pragma unroll
            for (int q = 0; q < 16; ++q) {
                *(f32x4*)&wi[q * 4] = *(const f32x4*)&gWih[(size_t)(c2 * 192 + tid) * 64 + q * 4];
                *(f32x4*)&wh[q * 4] = *(const f32x4*)&gWhh[(size_t)(c2 * 192 + tid) * 64 + q * 4];
            }
            bi = gbih[c2 * 192 + tid];
            bh = gbhh[c2 * 192 + tid];
        }
        if (tid < 64) hvg[tid] = 0.f;
        __syncthreads();
        for (int s = 0; s < 9; ++s) {
            int t = 108 + c2 * 9 + s;
            if (tid < 64) xvg[tid] = feats[(b * 144 + t) * 64 + tid];
            __syncthreads();
            if (tid < 192) {
                float ax = bi, ah = bh;
                float a0 = 0.f, a1 = 0.f, b0 = 0.f, b1 = 0.f;
                #pragma unroll
                for (int k = 0; k < 64; k += 2) {
                    a0 += wi[k] * xvg[k];     a1 += wi[k + 1] * xvg[k + 1];
                    b0 += wh[k] * hvg[k];     b1 += wh[k + 1] * hvg[k + 1];
                }
                gxl[tid] = ax + a0 + a1; ghl[tid] = ah + b0 + b1;
            }
            __syncthreads();
            if (tid < 64) {
                float xr = gxl[tid], xz = gxl[64 + tid], xn = gxl[128 + tid];
                float hr = ghl[tid], hz = ghl[64 + tid], hn = ghl[128 + tid];
                float rr = sigf(xr + hr), zz = sigf(xz + hz);
                float nn = tanh_(xn + rr * hn);
                h_s = (1.f - zz) * nn + zz * h_s;
                hvg[tid] = h_s;
                hst[s * 64 + tid] = h_s;
            }
            __syncthreads();
        }
        if (tid < 64) {
            int lane = tid;
            const float* Wc = aSW + c2 * 4096;
            float wcol[64];
            #pragma unroll
            for (int k = 0; k < 64; ++k) wcol[k] = Wc[k * 64 + lane];
            float bb = aSb[c2 * 64 + lane], vv = aSv[c2 * 64 + lane];
            float sv[9];
            #pragma unroll 1
            for (int s = 0; s < 9; ++s) {
                float acc = bb;
                #pragma unroll
                for (int q = 0; q < 16; ++q) {
                    f32x4 h4 = *(const f32x4*)&hst[s * 64 + q * 4];
                    acc += wcol[q * 4 + 0] * h4[0] + wcol[q * 4 + 1] * h4[1]
                         + wcol[q * 4 + 2] * h4[2] + wcol[q * 4 + 3] * h4[3];
                }
                float p = tanh_(acc) * vv;
                #pragma unroll
                for (int m = 1; m < 64; m <<= 1) p += __shfl_xor(p, m);
                sv[s] = p;
            }
            float mx = -3e38f;
            #pragma unroll
            for (int s = 0; s < 9; ++s) mx = fmaxf(mx, sv[s]);
            float ss = 0.f;
            #pragma unroll
            for (int s = 0; s < 9; ++s) { sv[s] = __expf(sv[s] - mx); ss += sv[s]; }
            float inv = 1.f / ss;
            float acc = 0.f;
            #pragma unroll
            for (int s = 0; s < 9; ++s) acc += sv[s] * inv * hst[s * 64 + lane];
            ctxS[(b * 4 + c2) * 64 + lane] = acc;
        }
    }
}

// ---------- K5: concat + lin1 + relu ----------
__global__ __launch_bounds__(512) void k_lin1(
    const float* __restrict__ ctxL, const float* __restrict__ ctxS,
    const float* __restrict__ W, const float* __restrict__ bb,
    float* __restrict__ h1) {
    int tid = threadIdx.x;
    __shared__ __align__(16) float fu[4 * 320];
    for (int c = tid; c < 1280; c += 512) {
        int b2 = c / 320, k = c % 320;
        fu[c] = (k < 64) ? ctxL[b2 * 64 + k] : ctxS[b2 * 256 + (k - 64)];
    }
    __syncthreads();
    int b = tid >> 7, r = tid & 127;
    float acc = bb[r];
    #pragma unroll 4
    for (int k4 = 0; k4 < 80; ++k4) {
        f32x4 w = *(const f32x4*)&W[r * 320 + k4 * 4];
        f32x4 x = *(const f32x4*)&fu[b * 320 + k4 * 4];
        acc += w[0] * x[0] + w[1] * x[1] + w[2] * x[2] + w[3] * x[3];
    }
    h1[b * 128 + r] = fmaxf(acc, 0.f);
}

// ---------- K6: lin2, streaming W. 1024 blocks, 4 lanes/row ----------
__global__ __launch_bounds__(256) void k_lin2(
    const float* __restrict__ h1, const float* __restrict__ W,
    const float* __restrict__ bb, float* __restrict__ h2) {
    __shared__ __align__(16) float h1l[512];
    int tid = threadIdx.x, blk = blockIdx.x;
    for (int c = tid; c < 512; c += 256) h1l[c] = h1[c];
    __syncthreads();
    int r = blk * 64 + (tid >> 2);
    int q = tid & 3;
    const float* wp = W + (size_t)r * 128 + q * 32;
    float a0 = 0.f, a1 = 0.f, a2 = 0.f, a3 = 0.f;
    #pragma unroll
    for (int i = 0; i < 8; ++i) {
        f32x4 w  = *(const f32x4*)(wp + i * 4);
        f32x4 x0 = *(const f32x4*)&h1l[q * 32 + i * 4];
        f32x4 x1 = *(const f32x4*)&h1l[128 + q * 32 + i * 4];
        f32x4 x2 = *(const f32x4*)&h1l[256 + q * 32 + i * 4];
        f32x4 x3 = *(const f32x4*)&h1l[384 + q * 32 + i * 4];
        a0 += w[0] * x0[0] + w[1] * x0[1] + w[2] * x0[2] + w[3] * x0[3];
        a1 += w[0] * x1[0] + w[1] * x1[1] + w[2] * x1[2] + w[3] * x1[3];
        a2 += w[0] * x2[0] + w[1] * x2[1] + w[2] * x2[2] + w[3] * x2[3];
        a3 += w[0] * x3[0] + w[1] * x3[1] + w[2] * x3[2] + w[3] * x3[3];
    }
    a0 += __shfl_xor(a0, 1); a0 += __shfl_xor(a0, 2);
    a1 += __shfl_xor(a1, 1); a1 += __shfl_xor(a1, 2);
    a2 += __shfl_xor(a2, 1); a2 += __shfl_xor(a2, 2);
    a3 += __shfl_xor(a3, 1); a3 += __shfl_xor(a3, 2);
    if (q == 0) {
        float bv = bb[r];
        h2[r]             = a0 + bv;
        h2[65536 + r]     = a1 + bv;
        h2[2 * 65536 + r] = a2 + bv;
        h2[3 * 65536 + r] = a3 + bv;
    }
}

// ---------- K7: 3x3 SAME conv + bias + softplus ----------
__global__ __launch_bounds__(256) void k_conv(
    const float* __restrict__ h2, const float* __restrict__ ck,
    const float* __restrict__ cb, float* __restrict__ out) {
    int x = threadIdx.x;
    int b = blockIdx.x >> 8, y = blockIdx.x & 255;
    float kk[9];
    #pragma unroll
    for (int i = 0; i < 9; ++i) kk[i] = ck[i];
    const float* base = h2 + b * 65536;
    float acc = cb[0];
    #pragma unroll
    for (int dy = -1; dy <= 1; ++dy) {
        int yy = y + dy;
        if (yy < 0 || yy > 255) continue;
        #pragma unroll
        for (int dx = -1; dx <= 1; ++dx) {
            int xx = x + dx;
            if (xx < 0 || xx > 255) continue;
            acc += base[yy * 256 + xx] * kk[(dy + 1) * 3 + (dx + 1)];
        }
    }
    float r = (acc > 20.f) ? acc : log1pf(__expf(acc));
    out[b * 65536 + y * 256 + x] = r;
}

extern "C" void kernel_launch(void* const* d_in, const int* in_sizes, int n_in,
                              void* d_out, int out_size, void* d_ws, size_t ws_size,
                              hipStream_t stream) {
    const float* seg   = (const float*)d_in[0];
    const float* adj   = (const float*)d_in[1];
    const float* dist  = (const float*)d_in[2];
    const float* W_gat = (const float*)d_in[3];
    const float* a_src = (const float*)d_in[4];
    const float* a_dst = (const float*)d_in[5];
    const float* lWih  = (const float*)d_in[6];
    const float* lWhh  = (const float*)d_in[7];
    const float* lbih  = (const float*)d_in[8];
    const float* lbhh  = (const float*)d_in[9];
    const float* aLW   = (const float*)d_in[10];
    const float* aLb   = (const float*)d_in[11];
    const float* aLv   = (const float*)d_in[12];
    const float* gWih  = (const float*)d_in[13];
    const float* gWhh  = (const float*)d_in[14];
    const float* gbih  = (const float*)d_in[15];
    const float* gbhh  = (const float*)d_in[16];
    const float* aSW   = (const float*)d_in[17];
    const float* aSb   = (const float*)d_in[18];
    const float* aSv   = (const float*)d_in[19];
    const float* l1W   = (const float*)d_in[20];
    const float* l1b   = (const float*)d_in[21];
    const float* l2W   = (const float*)d_in[22];
    const float* l2b   = (const float*)d_in[23];
    const float* ck    = (const float*)d_in[24];
    const float* cb    = (const float*)d_in[25];
    float* out = (float*)d_out;

    float* ws = (float*)d_ws;
    unsigned short* Mb  = (unsigned short*)ws;                    // 65536 ush
    unsigned short* Wt  = (unsigned short*)(ws + 32768);          // 16384 ush
    float* svec  = ws + 40960;                                    // 147456
    float* dvec  = svec + 147456;                                 // 147456
    float* smaxp = dvec + 147456;                                 // 2304
    float* dmaxp = smaxp + 2304;                                  // 2304
    unsigned short* WhT = (unsigned short*)(dmaxp + 2304);        // 9437184 ush
    float* feats = dmaxp + 2304 + 4718592;                        // 36864
    float* gx    = feats + 36864;                                 // 147456
    float* lout  = gx + 147456;                                   // 36864
    float* ctxL  = lout + 36864;                                  // 256
    float* ctxS  = ctxL + 256;                                    // 1024
    float* h1    = ctxS + 1024;                                   // 512
    float* h2    = h1 + 512;                                      // 262144

    k_prep<<<257, 256, 0, stream>>>(adj, dist, W_gat, Mb, Wt);
    k_gatA<<<2304, 256, 0, stream>>>(seg, Wt, a_src, a_dst, WhT, svec, dvec, smaxp, dmaxp);
    k_gatBF<<<576, 256, 0, stream>>>(WhT, svec, dvec, smaxp, dmaxp, Mb, lWih, lbih, lbhh, feats, gx);
    k_lstm<<<4, 64, 0, stream>>>(gx, lWhh, lout);
    k_ctx2<<<20, 256, 0, stream>>>(lout, aLW, aLb, aLv, feats, gWih, gWhh, gbih, gbhh,
                                   aSW, aSb, aSv, ctxL, ctxS);
    k_lin1<<<1, 512, 0, stream>>>(ctxL, ctxS, l1W, l1b, h1);
    k_lin2<<<1024, 256, 0, stream>>>(h1, l2W, l2b, h2);
    k_conv<<<1024, 256, 0, stream>>>(h2, ck, cb, out);
}

// Round 14
// 218.748 us; speedup vs baseline: 1.1451x; 1.1416x over previous
//
#include <hip/hip_runtime.h>
#include <hip/hip_bf16.h>
#include <cstddef>

// B=4, T=144, N=256, H=64, NC=4, CH=9, BT=576.
// Champion structure (230.9 us run) + two LSTM micro-cuts: rcp-based gates, f16-dot2 dot.
// Chain: prep -> gatA -> gatBF -> rnnctx (LSTM+GRU+attn pools, gx LDS-staged) -> lin1 -> lin2 -> conv.
// (~85 us of dur_us is an irreducible harness ws-fill.)

typedef __attribute__((ext_vector_type(8))) short bf16x8;
typedef __attribute__((ext_vector_type(4))) float f32x4;
typedef __fp16 h16x2 __attribute__((ext_vector_type(2)));

#if __has_builtin(__builtin_amdgcn_fdot2)
#define DOT2(a, b, c) __builtin_amdgcn_fdot2((a), (b), (c), false)
#else
#define DOT2(a, b, c) ((c) + (float)(a)[0] * (float)(b)[0] + (float)(a)[1] * (float)(b)[1])
#endif

__device__ __forceinline__ float rcp_(float x) { return __builtin_amdgcn_rcpf(x); }
__device__ __forceinline__ float sigf(float x) { return rcp_(1.0f + __expf(-x)); }
__device__ __forceinline__ float tanh_(float x) {
    x = fminf(fmaxf(x, -15.f), 15.f);
    float e = __expf(2.f * x);
    return (e - 1.f) * rcp_(e + 1.f);
}
__device__ __forceinline__ unsigned short f2b(float f) {
    unsigned u = __float_as_uint(f);
    u += 0x7FFFu + ((u >> 16) & 1u);
    return (unsigned short)(u >> 16);
}
__device__ __forceinline__ unsigned pk2(float lo, float hi) {
    __hip_bfloat162 h = __float22bfloat162_rn(float2{lo, hi});
    return *reinterpret_cast<unsigned*>(&h);
}
__device__ __forceinline__ float b2f(short s) {
    return __uint_as_float(((unsigned)(unsigned short)s) << 16);
}
__device__ __forceinline__ unsigned h2u2(h16x2 v) { return __builtin_bit_cast(unsigned, v); }
__device__ __forceinline__ h16x2 u2h2(unsigned u) { return __builtin_bit_cast(h16x2, u); }

// ---------- K1: Mb bf16 mask ; Wt bf16 [64 cols][256 k] ----------
__global__ void k_prep(const float* __restrict__ adj, const float* __restrict__ dist,
                       const float* __restrict__ W_gat,
                       unsigned short* __restrict__ Mb, unsigned short* __restrict__ Wt) {
    int blk = blockIdx.x, tid = threadIdx.x;
    if (blk < 256) {
        int i = blk * 256 + tid;
        Mb[i] = f2b((adj[i] > 0.f) ? -dist[i] : -1e9f);
    } else {
        for (int it = 0; it < 64; ++it) {
            int e = it * 256 + tid;
            int k = e >> 6, c = e & 63;
            Wt[c * 256 + k] = f2b(W_gat[e]);
        }
    }
}

// ---------- K2a: Wh GEMM. 2304 blocks (bt = blk>>2, sub = blk&3), 64 rows each ----------
__global__ __launch_bounds__(256, 6) void k_gatA(
    const float* __restrict__ seg, const unsigned short* __restrict__ Wt,
    const float* __restrict__ a_src, const float* __restrict__ a_dst,
    unsigned short* __restrict__ WhT, float* __restrict__ svec, float* __restrict__ dvec,
    float* __restrict__ smaxp, float* __restrict__ dmaxp) {
    __shared__ __align__(16) short A_s[64 * 64];
    __shared__ float red[8];

    const int tid  = threadIdx.x;
    const int lane = tid & 63;
    const int wv   = tid >> 6;
    const int blk  = blockIdx.x;
    const int bt   = blk >> 2;
    const int sub  = blk & 3;
    const float* __restrict__ segp = seg + (size_t)bt * 65536 + sub * 64 * 256;

    f32x4 acc[4];
    #pragma unroll
    for (int n = 0; n < 4; ++n) acc[n] = (f32x4)(0.f);

    for (int kc = 0; kc < 4; ++kc) {
        #pragma unroll
        for (int it = 0; it < 2; ++it) {
            int unit = it * 256 + tid;
            int row = unit >> 3, u = unit & 7;
            const float* g = segp + row * 256 + kc * 64 + u * 8;
            f32x4 v0 = *(const f32x4*)g;
            f32x4 v1 = *(const f32x4*)(g + 4);
            uint4 pk;
            pk.x = pk2(v0[0], v0[1]); pk.y = pk2(v0[2], v0[3]);
            pk.z = pk2(v1[0], v1[1]); pk.w = pk2(v1[2], v1[3]);
            *(uint4*)&A_s[(row * 8 + (u ^ (row & 7))) * 8] = pk;
        }
        bf16x8 bfr[2][4];
        #pragma unroll
        for (int kt2 = 0; kt2 < 2; ++kt2) {
            int ku = kt2 * 4 + (lane >> 4);
            #pragma unroll
            for (int nt = 0; nt < 4; ++nt) {
                int col = nt * 16 + (lane & 15);
                bfr[kt2][nt] = *(const bf16x8*)(Wt + col * 256 + kc * 64 + ku * 8);
            }
        }
        __syncthreads();
        int arow = wv * 16 + (lane & 15);
        #pragma unroll
        for (int kt2 = 0; kt2 < 2; ++kt2) {
            int ku = kt2 * 4 + (lane >> 4);
            bf16x8 afr = *(const bf16x8*)&A_s[(arow * 8 + (ku ^ (arow & 7))) * 8];
            #pragma unroll
            for (int nt = 0; nt < 4; ++nt)
                acc[nt] = __builtin_amdgcn_mfma_f32_16x16x32_bf16(afr, bfr[kt2][nt], acc[nt], 0, 0, 0);
        }
        __syncthreads();
    }

    float asv[4], adv[4];
    #pragma unroll
    for (int nt = 0; nt < 4; ++nt) {
        asv[nt] = a_src[nt * 16 + (lane & 15)];
        adv[nt] = a_dst[nt * 16 + (lane & 15)];
    }
    float mxs = -3e38f, mxd = -3e38f;
    int rowbase = sub * 64 + wv * 16;
    #pragma unroll
    for (int r = 0; r < 4; ++r) {
        float ps = acc[0][r] * asv[0] + acc[1][r] * asv[1] + acc[2][r] * asv[2] + acc[3][r] * asv[3];
        float pd = acc[0][r] * adv[0] + acc[1][r] * adv[1] + acc[2][r] * adv[2] + acc[3][r] * adv[3];
        #pragma unroll
        for (int m = 1; m < 16; m <<= 1) { ps += __shfl_xor(ps, m); pd += __shfl_xor(pd, m); }
        if ((lane & 15) == 0) {
            int row = rowbase + (lane >> 4) * 4 + r;
            svec[bt * 256 + row] = ps;
            dvec[bt * 256 + row] = pd;
        }
        mxs = fmaxf(mxs, ps); mxd = fmaxf(mxd, pd);
    }
    mxs = fmaxf(mxs, __shfl_xor(mxs, 16)); mxs = fmaxf(mxs, __shfl_xor(mxs, 32));
    mxd = fmaxf(mxd, __shfl_xor(mxd, 16)); mxd = fmaxf(mxd, __shfl_xor(mxd, 32));
    if (lane == 0) { red[wv] = mxs; red[4 + wv] = mxd; }

    {
        int c = lane & 15, q = lane >> 4;
        int kt2  = wv >> 1;
        int oct  = (wv & 1) * 2 + (q >> 1);
        int laneP = oct * 16 + c;
        int e0b  = (q & 1) * 8;
        #pragma unroll
        for (int nt = 0; nt < 4; ++nt) {
            uint2 pk4;
            pk4.x = pk2(acc[nt][0], acc[nt][1]);
            pk4.y = pk2(acc[nt][2], acc[nt][3]);
            *(uint2*)((char*)A_s + (((kt2 * 4 + nt) * 64 + laneP) * 16 + e0b)) = pk4;
        }
    }
    __syncthreads();
    {
        const uint4* Fs = (const uint4*)A_s;
        uint4* Gd = (uint4*)(WhT + (size_t)bt * 16384 + sub * 4096);
        Gd[tid] = Fs[tid];
        Gd[256 + tid] = Fs[256 + tid];
    }
    if (tid == 0) {
        smaxp[blk] = fmaxf(fmaxf(red[0], red[1]), fmaxf(red[2], red[3]));
        dmaxp[blk] = fmaxf(fmaxf(red[4], red[5]), fmaxf(red[6], red[7]));
    }
}

// ---------- K2b: fused exp+PV+normalize+elu+mean+gx. One block per bt (576 blocks) ----------
__global__ __launch_bounds__(256, 4) void k_gatBF(
    const unsigned short* __restrict__ WhT, const float* __restrict__ svec,
    const float* __restrict__ dvec, const float* __restrict__ smaxp,
    const float* __restrict__ dmaxp, const unsigned short* __restrict__ Mb,
    const float* __restrict__ lWih, const float* __restrict__ lbih,
    const float* __restrict__ lbhh, float* __restrict__ feats, float* __restrict__ gx) {
    __shared__ __align__(16) float dv_l[256];
    __shared__ float red[256];
    __shared__ __align__(16) float feats_l[64];

    const int tid  = threadIdx.x;
    const int lane = tid & 63;
    const int wv   = tid >> 6;
    const int wrow = wv * 64;
    const int bt   = blockIdx.x;
    const unsigned short* __restrict__ Wp = WhT + (size_t)bt * 16384;

    dv_l[tid] = dvec[bt * 256 + tid];
    float mB;
    {
        float ms = fmaxf(fmaxf(smaxp[bt * 4], smaxp[bt * 4 + 1]),
                         fmaxf(smaxp[bt * 4 + 2], smaxp[bt * 4 + 3]));
        float md = fmaxf(fmaxf(dmaxp[bt * 4], dmaxp[bt * 4 + 1]),
                         fmaxf(dmaxp[bt * 4 + 2], dmaxp[bt * 4 + 3]));
        float x = ms + md;
        mB = fmaxf(x, 0.2f * x);
    }
    float sv4[4];
    #pragma unroll
    for (int mt = 0; mt < 4; ++mt) sv4[mt] = svec[bt * 256 + wrow + mt * 16 + (lane & 15)];
    __syncthreads();

    f32x4 acc2[4][4];
    #pragma unroll
    for (int a = 0; a < 4; ++a)
        #pragma unroll
        for (int b = 0; b < 4; ++b) acc2[a][b] = (f32x4)(0.f);
    float psum[4] = {0.f, 0.f, 0.f, 0.f};
    const int jbase = (lane >> 4) * 8;

    #pragma unroll 1
    for (int kt = 0; kt < 8; ++kt) {
        int j0 = kt * 32 + jbase;
        bf16x8 bfr[4];
        #pragma unroll
        for (int nt = 0; nt < 4; ++nt)
            bfr[nt] = *(const bf16x8*)(Wp + ((kt * 4 + nt) * 64 + lane) * 8);
        f32x4 d0 = *(const f32x4*)&dv_l[j0];
        f32x4 d1 = *(const f32x4*)&dv_l[j0 + 4];
        #pragma unroll
        for (int mt = 0; mt < 4; ++mt) {
            int prow = wrow + mt * 16 + (lane & 15);
            bf16x8 mrow = *(const bf16x8*)(Mb + prow * 256 + j0);
            float p[8];
            #pragma unroll
            for (int e = 0; e < 4; ++e) {
                float u = sv4[mt] + d0[e];
                u = fmaxf(u, 0.2f * u);
                p[e] = __expf(u + b2f(mrow[e]) - mB);
                float w = sv4[mt] + d1[e];
                w = fmaxf(w, 0.2f * w);
                p[4 + e] = __expf(w + b2f(mrow[4 + e]) - mB);
            }
            psum[mt] += ((p[0] + p[1]) + (p[2] + p[3])) + ((p[4] + p[5]) + (p[6] + p[7]));
            uint4 upf;
            upf.x = pk2(p[0], p[1]); upf.y = pk2(p[2], p[3]);
            upf.z = pk2(p[4], p[5]); upf.w = pk2(p[6], p[7]);
            bf16x8 pf = *reinterpret_cast<bf16x8*>(&upf);
            #pragma unroll
            for (int nt = 0; nt < 4; ++nt)
                acc2[mt][nt] = __builtin_amdgcn_mfma_f32_16x16x32_bf16(pf, bfr[nt], acc2[mt][nt], 0, 0, 0);
        }
    }
    #pragma unroll
    for (int mt = 0; mt < 4; ++mt) {
        psum[mt] += __shfl_xor(psum[mt], 16);
        psum[mt] += __shfl_xor(psum[mt], 32);
    }

    float part[4] = {0.f, 0.f, 0.f, 0.f};
    #pragma unroll
    for (int mt = 0; mt < 4; ++mt) {
        #pragma unroll
        for (int r = 0; r < 4; ++r) {
            float rs  = __shfl(psum[mt], ((lane >> 4) << 2) + r);
            float inv = 1.0f / rs;
            #pragma unroll
            for (int nt = 0; nt < 4; ++nt) {
                float x = acc2[mt][nt][r] * inv;
                x = (x > 0.f) ? x : expm1f(x);
                part[nt] += x;
            }
        }
    }
    #pragma unroll
    for (int nt = 0; nt < 4; ++nt) {
        part[nt] += __shfl_xor(part[nt], 16);
        part[nt] += __shfl_xor(part[nt], 32);
    }
    if ((lane >> 4) == 0) {
        #pragma unroll
        for (int nt = 0; nt < 4; ++nt) red[wv * 64 + nt * 16 + lane] = part[nt];
    }
    __syncthreads();
    if (tid < 64) {
        float f = (red[tid] + red[64 + tid] + red[128 + tid] + red[192 + tid]) * (1.0f / 256.0f);
        feats[bt * 64 + tid] = f;
        feats_l[tid] = f;
    }
    __syncthreads();
    {
        float a = lbih[tid] + lbhh[tid];
        const float* wp = lWih + tid * 64;
        #pragma unroll
        for (int k4 = 0; k4 < 16; ++k4) {
            f32x4 w = *(const f32x4*)(wp + k4 * 4);
            f32x4 x = *(const f32x4*)&feats_l[k4 * 4];
            a += w[0] * x[0] + w[1] * x[1] + w[2] * x[2] + w[3] * x[3];
        }
        gx[bt * 256 + tid] = a;
    }
}

// ---------- K3: LSTM+attnL (blocks 0-3, gx LDS-staged, f16-dot2) ; GRU+attnS (blocks 4-19) ----------
__global__ __launch_bounds__(256) void k_rnnctx(
    const float* __restrict__ gx, const float* __restrict__ lWhh,
    const float* __restrict__ aLW, const float* __restrict__ aLb, const float* __restrict__ aLv,
    const float* __restrict__ feats, const float* __restrict__ gWih,
    const float* __restrict__ gWhh, const float* __restrict__ gbih,
    const float* __restrict__ gbhh, const float* __restrict__ aSW,
    const float* __restrict__ aSb, const float* __restrict__ aSv,
    float* __restrict__ ctxL, float* __restrict__ ctxS) {
    // gxl[144*256] (h history overwrites consumed rows) + gl[2*256] + sc[144] + al[144]
    __shared__ __align__(16) float smem[37664];   // 150.7 KB
    int tid = threadIdx.x;
    if (blockIdx.x < 4) {
        int b = blockIdx.x;
        int lane = tid & 63, wv = tid >> 6;
        float* gxl = smem;              // [144][256]; row t's first 64 = h[t] after step t
        float* gl  = smem + 36864;      // [2][256]
        float* sc  = smem + 37376;      // [144]
        float* al  = smem + 37520;      // [144]
        // this thread's gate row (row = tid) as 32 f16 pairs (32 VGPRs)
        h16x2 wr2[32];
        #pragma unroll
        for (int q = 0; q < 8; ++q) {
            f32x4 a0 = *(const f32x4*)&lWhh[(size_t)tid * 64 + q * 8];
            f32x4 a1 = *(const f32x4*)&lWhh[(size_t)tid * 64 + q * 8 + 4];
            wr2[4*q]   = __builtin_amdgcn_cvt_pkrtz(a0[0], a0[1]);
            wr2[4*q+1] = __builtin_amdgcn_cvt_pkrtz(a0[2], a0[3]);
            wr2[4*q+2] = __builtin_amdgcn_cvt_pkrtz(a1[0], a1[1]);
            wr2[4*q+3] = __builtin_amdgcn_cvt_pkrtz(a1[2], a1[3]);
        }
        // Stage all gx for this batch into LDS (coalesced float4), one-time drain.
        {
            const float* gxb = gx + (size_t)b * 36864;
            #pragma unroll
            for (int it = 0; it < 36; ++it) {
                int idx = it * 1024 + tid * 4;
                *(f32x4*)&gxl[idx] = *(const f32x4*)(gxb + idx);
            }
        }
        __syncthreads();
        float c_s = 0.f;
        float hprev = 0.f;                       // lane l holds h[l], replicated per wave
        float gx_cur = gxl[tid];
        for (int t = 0; t < 144; ++t) {
            float gx_next = (t < 143) ? gxl[(t + 1) * 256 + tid] : 0.f;
            // pack h pairs: lane 2q holds (h[2q],h[2q+1]) after cvt; readlane even lanes
            float hsw = __shfl_xor(hprev, 1);
            unsigned hpu = h2u2(__builtin_amdgcn_cvt_pkrtz(hprev, hsw));
            float s0 = 0.f, s1 = 0.f;
            #pragma unroll
            for (int q = 0; q < 32; q += 2) {
                h16x2 hv0 = u2h2((unsigned)__builtin_amdgcn_readlane((int)hpu, 2 * q));
                h16x2 hv1 = u2h2((unsigned)__builtin_amdgcn_readlane((int)hpu, 2 * q + 2));
                s0 = DOT2(wr2[q], hv0, s0);
                s1 = DOT2(wr2[q + 1], hv1, s1);
            }
            float a = gx_cur + s0 + s1;
            gl[(t & 1) * 256 + tid] = a;
            __syncthreads();                     // pure-LDS loop: drains lgkm only (cheap)
            float ig = gl[(t & 1) * 256 + lane],       fg = gl[(t & 1) * 256 + 64 + lane],
                  gg = gl[(t & 1) * 256 + 128 + lane], og = gl[(t & 1) * 256 + 192 + lane];
            c_s = sigf(fg) * c_s + sigf(ig) * tanh_(gg);
            float h = sigf(og) * tanh_(c_s);
            hprev = h;
            if (wv == 0) gxl[t * 256 + lane] = h;   // row t consumed; store h history
            gx_cur = gx_next;
        }
        __syncthreads();
        // attnL scores from h history (rows of gxl, stride 256; broadcast reads)
        float wcol[64];
        #pragma unroll
        for (int k = 0; k < 64; ++k) wcol[k] = aLW[k * 64 + lane];
        float bb = aLb[lane], vv = aLv[lane];
        for (int g = 0; g < 36; ++g) {
            int t = g * 4 + wv;
            float acc = bb;
            #pragma unroll
            for (int q = 0; q < 16; ++q) {
                f32x4 h4 = *(const f32x4*)&gxl[t * 256 + q * 4];
                acc += wcol[q * 4 + 0] * h4[0] + wcol[q * 4 + 1] * h4[1]
                     + wcol[q * 4 + 2] * h4[2] + wcol[q * 4 + 3] * h4[3];
            }
            float p = tanh_(acc) * vv;
            #pragma unroll
            for (int m = 1; m < 64; m <<= 1) p += __shfl_xor(p, m);
            if (lane == 0) sc[t] = p;
        }
        __syncthreads();
        float mx = -3e38f;
        for (int t2 = 0; t2 < 144; ++t2) mx = fmaxf(mx, sc[t2]);
        float ss = 0.f;
        for (int t2 = 0; t2 < 144; ++t2) ss += __expf(sc[t2] - mx);
        float inv = 1.f / ss;
        if (tid < 144) al[tid] = __expf(sc[tid] - mx) * inv;
        __syncthreads();
        if (tid < 64) {
            float acc = 0.f;
            for (int t2 = 0; t2 < 144; ++t2) acc += al[t2] * gxl[t2 * 256 + tid];
            ctxL[b * 64 + tid] = acc;
        }
    } else {
        int bi_ = blockIdx.x - 4;
        int b = bi_ >> 2, c2 = bi_ & 3;
        float* hvg = smem;
        float* xvg = smem + 64;
        float* gxl = smem + 128;
        float* ghl = smem + 320;
        float* hst = smem + 512;        // [9][64]
        float wi[64], wh[64], bi = 0.f, bh = 0.f, h_s = 0.f;
        if (tid < 192) {
            #pragma unroll
            for (int q = 0; q < 16; ++q) {
                *(f32x4*)&wi[q * 4] = *(const f32x4*)&gWih[(size_t)(c2 * 192 + tid) * 64 + q * 4];
                *(f32x4*)&wh[q * 4] = *(const f32x4*)&gWhh[(size_t)(c2 * 192 + tid) * 64 + q * 4];
            }
            bi = gbih[c2 * 192 + tid];
            bh = gbhh[c2 * 192 + tid];
        }
        if (tid < 64) hvg[tid] = 0.f;
        __syncthreads();
        for (int s = 0; s < 9; ++s) {
            int t = 108 + c2 * 9 + s;
            if (tid < 64) xvg[tid] = feats[(b * 144 + t) * 64 + tid];
            __syncthreads();
            if (tid < 192) {
                float ax = bi, ah = bh;
                float a0 = 0.f, a1 = 0.f, b0 = 0.f, b1 = 0.f;
                #pragma unroll
                for (int k = 0; k < 64; k += 2) {
                    a0 += wi[k] * xvg[k];     a1 += wi[k + 1] * xvg[k + 1];
                    b0 += wh[k] * hvg[k];     b1 += wh[k + 1] * hvg[k + 1];
                }
                gxl[tid] = ax + a0 + a1; ghl[tid] = ah + b0 + b1;
            }
            __syncthreads();
            if (tid < 64) {
                float xr = gxl[tid], xz = gxl[64 + tid], xn = gxl[128 + tid];
                float hr = ghl[tid], hz = ghl[64 + tid], hn = ghl[128 + tid];
                float rr = sigf(xr + hr), zz = sigf(xz + hz);
                float nn = tanh_(xn + rr * hn);
                h_s = (1.f - zz) * nn + zz * h_s;
                hvg[tid] = h_s;
                hst[s * 64 + tid] = h_s;
            }
            __syncthreads();
        }
        if (tid < 64) {
            int lane = tid;
            const float* Wc = aSW + c2 * 4096;
            float wcol[64];
            #pragma unroll
            for (int k = 0; k < 64; ++k) wcol[k] = Wc[k * 64 + lane];
            float bb = aSb[c2 * 64 + lane], vv = aSv[c2 * 64 + lane];
            float sv[9];
            #pragma unroll 1
            for (int s = 0; s < 9; ++s) {
                float acc = bb;
                #pragma unroll
                for (int q = 0; q < 16; ++q) {
                    f32x4 h4 = *(const f32x4*)&hst[s * 64 + q * 4];
                    acc += wcol[q * 4 + 0] * h4[0] + wcol[q * 4 + 1] * h4[1]
                         + wcol[q * 4 + 2] * h4[2] + wcol[q * 4 + 3] * h4[3];
                }
                float p = tanh_(acc) * vv;
                #pragma unroll
                for (int m = 1; m < 64; m <<= 1) p += __shfl_xor(p, m);
                sv[s] = p;
            }
            float mx = -3e38f;
            #pragma unroll
            for (int s = 0; s < 9; ++s) mx = fmaxf(mx, sv[s]);
            float ss = 0.f;
            #pragma unroll
            for (int s = 0; s < 9; ++s) { sv[s] = __expf(sv[s] - mx); ss += sv[s]; }
            float inv = 1.f / ss;
            float acc = 0.f;
            #pragma unroll
            for (int s = 0; s < 9; ++s) acc += sv[s] * inv * hst[s * 64 + lane];
            ctxS[(b * 4 + c2) * 64 + lane] = acc;
        }
    }
}

// ---------- K5: concat + lin1 + relu ----------
__global__ __launch_bounds__(512) void k_lin1(
    const float* __restrict__ ctxL, const float* __restrict__ ctxS,
    const float* __restrict__ W, const float* __restrict__ bb,
    float* __restrict__ h1) {
    int tid = threadIdx.x;
    __shared__ __align__(16) float fu[4 * 320];
    for (int c = tid; c < 1280; c += 512) {
        int b2 = c / 320, k = c % 320;
        fu[c] = (k < 64) ? ctxL[b2 * 64 + k] : ctxS[b2 * 256 + (k - 64)];
    }
    __syncthreads();
    int b = tid >> 7, r = tid & 127;
    float acc = bb[r];
    #pragma unroll 4
    for (int k4 = 0; k4 < 80; ++k4) {
        f32x4 w = *(const f32x4*)&W[r * 320 + k4 * 4];
        f32x4 x = *(const f32x4*)&fu[b * 320 + k4 * 4];
        acc += w[0] * x[0] + w[1] * x[1] + w[2] * x[2] + w[3] * x[3];
    }
    h1[b * 128 + r] = fmaxf(acc, 0.f);
}

// ---------- K6: lin2, streaming W. 1024 blocks, 4 lanes/row ----------
__global__ __launch_bounds__(256) void k_lin2(
    const float* __restrict__ h1, const float* __restrict__ W,
    const float* __restrict__ bb, float* __restrict__ h2) {
    __shared__ __align__(16) float h1l[512];
    int tid = threadIdx.x, blk = blockIdx.x;
    for (int c = tid; c < 512; c += 256) h1l[c] = h1[c];
    __syncthreads();
    int r = blk * 64 + (tid >> 2);
    int q = tid & 3;
    const float* wp = W + (size_t)r * 128 + q * 32;
    float a0 = 0.f, a1 = 0.f, a2 = 0.f, a3 = 0.f;
    #pragma unroll
    for (int i = 0; i < 8; ++i) {
        f32x4 w  = *(const f32x4*)(wp + i * 4);
        f32x4 x0 = *(const f32x4*)&h1l[q * 32 + i * 4];
        f32x4 x1 = *(const f32x4*)&h1l[128 + q * 32 + i * 4];
        f32x4 x2 = *(const f32x4*)&h1l[256 + q * 32 + i * 4];
        f32x4 x3 = *(const f32x4*)&h1l[384 + q * 32 + i * 4];
        a0 += w[0] * x0[0] + w[1] * x0[1] + w[2] * x0[2] + w[3] * x0[3];
        a1 += w[0] * x1[0] + w[1] * x1[1] + w[2] * x1[2] + w[3] * x1[3];
        a2 += w[0] * x2[0] + w[1] * x2[1] + w[2] * x2[2] + w[3] * x2[3];
        a3 += w[0] * x3[0] + w[1] * x3[1] + w[2] * x3[2] + w[3] * x3[3];
    }
    a0 += __shfl_xor(a0, 1); a0 += __shfl_xor(a0, 2);
    a1 += __shfl_xor(a1, 1); a1 += __shfl_xor(a1, 2);
    a2 += __shfl_xor(a2, 1); a2 += __shfl_xor(a2, 2);
    a3 += __shfl_xor(a3, 1); a3 += __shfl_xor(a3, 2);
    if (q == 0) {
        float bv = bb[r];
        h2[r]             = a0 + bv;
        h2[65536 + r]     = a1 + bv;
        h2[2 * 65536 + r] = a2 + bv;
        h2[3 * 65536 + r] = a3 + bv;
    }
}

// ---------- K7: 3x3 SAME conv + bias + softplus ----------
__global__ __launch_bounds__(256) void k_conv(
    const float* __restrict__ h2, const float* __restrict__ ck,
    const float* __restrict__ cb, float* __restrict__ out) {
    int x = threadIdx.x;
    int b = blockIdx.x >> 8, y = blockIdx.x & 255;
    float kk[9];
    #pragma unroll
    for (int i = 0; i < 9; ++i) kk[i] = ck[i];
    const float* base = h2 + b * 65536;
    float acc = cb[0];
    #pragma unroll
    for (int dy = -1; dy <= 1; ++dy) {
        int yy = y + dy;
        if (yy < 0 || yy > 255) continue;
        #pragma unroll
        for (int dx = -1; dx <= 1; ++dx) {
            int xx = x + dx;
            if (xx < 0 || xx > 255) continue;
            acc += base[yy * 256 + xx] * kk[(dy + 1) * 3 + (dx + 1)];
        }
    }
    float r = (acc > 20.f) ? acc : log1pf(__expf(acc));
    out[b * 65536 + y * 256 + x] = r;
}

extern "C" void kernel_launch(void* const* d_in, const int* in_sizes, int n_in,
                              void* d_out, int out_size, void* d_ws, size_t ws_size,
                              hipStream_t stream) {
    const float* seg   = (const float*)d_in[0];
    const float* adj   = (const float*)d_in[1];
    const float* dist  = (const float*)d_in[2];
    const float* W_gat = (const float*)d_in[3];
    const float* a_src = (const float*)d_in[4];
    const float* a_dst = (const float*)d_in[5];
    const float* lWih  = (const float*)d_in[6];
    const float* lWhh  = (const float*)d_in[7];
    const float* lbih  = (const float*)d_in[8];
    const float* lbhh  = (const float*)d_in[9];
    const float* aLW   = (const float*)d_in[10];
    const float* aLb   = (const float*)d_in[11];
    const float* aLv   = (const float*)d_in[12];
    const float* gWih  = (const float*)d_in[13];
    const float* gWhh  = (const float*)d_in[14];
    const float* gbih  = (const float*)d_in[15];
    const float* gbhh  = (const float*)d_in[16];
    const float* aSW   = (const float*)d_in[17];
    const float* aSb   = (const float*)d_in[18];
    const float* aSv   = (const float*)d_in[19];
    const float* l1W   = (const float*)d_in[20];
    const float* l1b   = (const float*)d_in[21];
    const float* l2W   = (const float*)d_in[22];
    const float* l2b   = (const float*)d_in[23];
    const float* ck    = (const float*)d_in[24];
    const float* cb    = (const float*)d_in[25];
    float* out = (float*)d_out;

    float* ws = (float*)d_ws;
    unsigned short* Mb  = (unsigned short*)ws;                    // 65536 ush
    unsigned short* Wt  = (unsigned short*)(ws + 32768);          // 16384 ush
    float* svec  = ws + 40960;                                    // 147456
    float* dvec  = svec + 147456;                                 // 147456
    float* smaxp = dvec + 147456;                                 // 2304
    float* dmaxp = smaxp + 2304;                                  // 2304
    unsigned short* WhT = (unsigned short*)(dmaxp + 2304);        // 9437184 ush
    float* feats = dmaxp + 2304 + 4718592;                        // 36864
    float* gx    = feats + 36864;                                 // 147456
    float* ctxL  = gx + 147456;                                   // 256
    float* ctxS  = ctxL + 256;                                    // 1024
    float* h1    = ctxS + 1024;                                   // 512
    float* h2    = h1 + 512;                                      // 262144

    k_prep<<<257, 256, 0, stream>>>(adj, dist, W_gat, Mb, Wt);
    k_gatA<<<2304, 256, 0, stream>>>(seg, Wt, a_src, a_dst, WhT, svec, dvec, smaxp, dmaxp);
    k_gatBF<<<576, 256, 0, stream>>>(WhT, svec, dvec, smaxp, dmaxp, Mb, lWih, lbih, lbhh, feats, gx);
    k_rnnctx<<<20, 256, 0, stream>>>(gx, lWhh, aLW, aLb, aLv, feats, gWih, gWhh, gbih, gbhh,
                                     aSW, aSb, aSv, ctxL, ctxS);
    k_lin1<<<1, 512, 0, stream>>>(ctxL, ctxS, l1W, l1b, h1);
    k_lin2<<<1024, 256, 0, stream>>>(h1, l2W, l2b, h2);
    k_conv<<<1024, 256, 0, stream>>>(h2, ck, cb, out);
}